// Round 3
// baseline (689.826 us; speedup 1.0000x reference)
//
#include <hip/hip_runtime.h>
#include <stdint.h>

// WordLSTMCell: c1 = sigmoid(f)*c0 + sigmoid(i)*tanh(c),
//   [f|i|c] = x@W + h@Wh + b ;  x:[8192,1024] h,c0:[8192,2048]
//   W:[1024,6144] Wh:[2048,6144] b:[6144]  (fp32; out fp32 [8192,2048])
//
// Round 3: the 2-barrier K-loop was the bottleneck (vmcnt(0) drain before
// s_barrier serializes full memory latency every kt; MfmaUtil stuck at 29%).
// Fix: NO LDS, NO barriers in the GEMM. With packed layouts
// Ap[kt][m][32], Bp[kt][n][32], every MFMA fragment is a fully coalesced
// 16B/lane register-direct load (16 rows x 64B = 1KB/wave). unroll-2 lets
// the compiler keep next-kt loads in flight behind current MFMAs with
// fine-grained vmcnt. pack_b rebuilt: coalesced reads -> LDS transpose
// (stride 522 = bank-stride 5, coprime 32: gather conflict-free) ->
// coalesced stores.

#define BATCH 8192
#define INSZ  1024
#define HID   2048
#define NG    6144
#define KTOT  3072
#define KTILES 96

typedef __attribute__((ext_vector_type(8))) short short8;
typedef __attribute__((ext_vector_type(4))) short short4v;
typedef __attribute__((ext_vector_type(4))) float f32x4;
typedef __attribute__((ext_vector_type(2))) unsigned short u16x2;
typedef __attribute__((ext_vector_type(4))) unsigned short u16x4;

__device__ __forceinline__ unsigned short f32_to_bf16(float f) {
  uint32_t u = __builtin_bit_cast(uint32_t, f);
  u += 0x7fffu + ((u >> 16) & 1u);   // round-to-nearest-even
  return (unsigned short)(u >> 16);
}

// ---------------- pack kernels ----------------

// Apack[kt][m][kk] = concat(x,h)[m][kt*32+kk], bf16, plain layout. 48 MB.
__global__ __launch_bounds__(256) void pack_a_kernel(
    const float* __restrict__ x, const float* __restrict__ h,
    unsigned short* __restrict__ Ap) {
  uint32_t q   = blockIdx.x * 256u + threadIdx.x;  // [0, 96*8192*8)
  uint32_t kk4 = q & 7u;
  uint32_t m   = (q >> 3) & 8191u;
  uint32_t kt  = q >> 16;
  uint32_t k   = kt * 32u + kk4 * 4u;
  const float* src = (k < INSZ) ? (x + (size_t)m * INSZ + k)
                                : (h + (size_t)m * HID + (k - INSZ));
  float4 v = *(const float4*)src;
  u16x4 o;
  o.x = f32_to_bf16(v.x); o.y = f32_to_bf16(v.y);
  o.z = f32_to_bf16(v.z); o.w = f32_to_bf16(v.w);
  *(u16x4*)(Ap + ((size_t)kt * BATCH + m) * 32 + kk4 * 4) = o;
}

// Bpack[kt][n][kk] = vstack(W,Wh)[kt*32+kk][n], bf16. 36 MB.
// Per block: 32k x 512n tile. Coalesced float4 reads, LDS transpose with
// row stride 522 shorts (bank stride 5 — gather phase conflict-free),
// fully coalesced u16x4 stores.
__global__ __launch_bounds__(256) void pack_b_kernel(
    const float* __restrict__ W, const float* __restrict__ Wh,
    unsigned short* __restrict__ Bp) {
  __shared__ unsigned short tile[32 * 522];  // [kk][n], 33.4 KB
  const int tid = threadIdx.x;
  const int kt = blockIdx.x / 12;
  const int n0 = (blockIdx.x % 12) * 512;
  const int k0 = kt * 32;
  const float* base; int kb;
  if (k0 < INSZ) { base = W;  kb = k0; }
  else           { base = Wh; kb = k0 - INSZ; }
#pragma unroll
  for (int i = 0; i < 16; ++i) {
    int t  = i * 256 + tid;            // 4096 float4 tasks
    int kk = t >> 7, n4 = (t & 127) * 4;
    float4 v = *(const float4*)(base + (size_t)(kb + kk) * NG + n0 + n4);
    u16x2 lo, hi;
    lo.x = f32_to_bf16(v.x); lo.y = f32_to_bf16(v.y);
    hi.x = f32_to_bf16(v.z); hi.y = f32_to_bf16(v.w);
    *(u16x2*)(tile + kk * 522 + n4)     = lo;   // dword-aligned b32 stores
    *(u16x2*)(tile + kk * 522 + n4 + 2) = hi;
  }
  __syncthreads();
#pragma unroll
  for (int i = 0; i < 16; ++i) {
    int o = i * 256 + tid;             // 4096 u16x4 tasks: n = o>>3, u = o&7
    int n = o >> 3, u = o & 7;
    u16x4 val;
    val.x = tile[(u * 4 + 0) * 522 + n];
    val.y = tile[(u * 4 + 1) * 522 + n];
    val.z = tile[(u * 4 + 2) * 522 + n];
    val.w = tile[(u * 4 + 3) * 522 + n];
    *(u16x4*)(Bp + ((size_t)kt * NG + n0 + n) * 32 + u * 4) = val;
  }
}

// ---------------- shared epilogue ----------------
// C-layout (m89-verified): col = lane&15, row = (lane>>4)*4 + reg.
__device__ __forceinline__ void lstm_epilogue(
    const f32x4 acc[4][6], int m0, int j0, int wm, int wn, int quad, int l16,
    const float* __restrict__ bias, const float* __restrict__ c0,
    float* __restrict__ out) {
#pragma unroll
  for (int mi = 0; mi < 4; ++mi) {
    int rowb = m0 + wm * 64 + mi * 16 + quad * 4;
#pragma unroll
    for (int p = 0; p < 2; ++p) {
      int j = j0 + (2 * wn + p) * 16 + l16;
      float bfv = bias[j], biv = bias[HID + j], bcv = bias[2 * HID + j];
#pragma unroll
      for (int r = 0; r < 4; ++r) {
        size_t idx = (size_t)(rowb + r) * HID + j;
        float fg = acc[mi][0 + p][r] + bfv;
        float ig = acc[mi][2 + p][r] + biv;
        float cg = acc[mi][4 + p][r] + bcv;
        float sf = 1.f / (1.f + __expf(-fg));
        float si = 1.f / (1.f + __expf(-ig));
        float th = 2.f / (1.f + __expf(-2.f * cg)) - 1.f;
        out[idx] = sf * c0[idx] + si * th;
      }
    }
  }
}

// ---------------- GEMM: pure register streaming, no LDS, no barriers ------
__global__ __launch_bounds__(256, 2) void gemm_stream_kernel(
    const unsigned short* __restrict__ Ap, const unsigned short* __restrict__ Bp,
    const float* __restrict__ bias, const float* __restrict__ c0,
    float* __restrict__ out) {
  const int tid = threadIdx.x;
  const int lane = tid & 63, w = tid >> 6;
  const int wm = w >> 1, wn = w & 1;       // waves 2(M) x 2(N-pairs)
  const int quad = lane >> 4, l16 = lane & 15;
  const int bx = blockIdx.x;
  const int mt = bx & 63, jt = bx >> 6;    // consecutive blocks share jt (B in L1/L2)
  const int m0 = mt * 128, j0 = jt * 64;

  f32x4 acc[4][6];
#pragma unroll
  for (int a = 0; a < 4; ++a)
#pragma unroll
    for (int b = 0; b < 6; ++b) acc[a][b] = (f32x4){0.f, 0.f, 0.f, 0.f};

  // af[mi]: rows (m0+wm*64+mi*16+l16) of Ap, 16B at quad*8 — wave = 1KB contig
  const unsigned short* pa = Ap + ((size_t)(m0 + wm * 64 + l16)) * 32 + quad * 8;
  // bf[g,p]: rows (g*HID + j0 + (2wn+p)*16 + l16) of Bp — wave = 1KB contig
  const unsigned short* pb = Bp + ((size_t)(j0 + 2 * wn * 16 + l16)) * 32 + quad * 8;

#pragma unroll 2
  for (int kt = 0; kt < KTILES; ++kt) {
    short8 af[4], bf[6];
#pragma unroll
    for (int mi = 0; mi < 4; ++mi)
      af[mi] = *(const short8*)(pa + mi * 512);
#pragma unroll
    for (int g = 0; g < 3; ++g)
#pragma unroll
      for (int p = 0; p < 2; ++p)
        bf[g * 2 + p] = *(const short8*)(pb + g * (HID * 32) + p * 512);
#pragma unroll
    for (int mi = 0; mi < 4; ++mi)
#pragma unroll
      for (int f = 0; f < 6; ++f)
        acc[mi][f] =
            __builtin_amdgcn_mfma_f32_16x16x32_bf16(af[mi], bf[f], acc[mi][f], 0, 0, 0);
    pa += (size_t)BATCH * 32;
    pb += (size_t)NG * 32;
  }
  lstm_epilogue(acc, m0, j0, wm, wn, quad, l16, bias, c0, out);
}

// ---------------- Path B GEMM: fp32 staging fallback (no workspace) --------
__global__ __launch_bounds__(256) void gemm_f32_kernel(
    const float* __restrict__ x, const float* __restrict__ h,
    const float* __restrict__ W, const float* __restrict__ Wh,
    const float* __restrict__ bias, const float* __restrict__ c0,
    float* __restrict__ out) {
  __shared__ __align__(16) unsigned short As[128 * 36];
  __shared__ __align__(16) unsigned short Bs[192 * 36];
  const int tid = threadIdx.x;
  const int lane = tid & 63, w = tid >> 6;
  const int wm = w >> 1, wn = w & 1;
  const int quad = lane >> 4, l16 = lane & 15;
  const int bx = blockIdx.x;
  const int jt = bx & 31, mt = bx >> 5;
  const int m0 = mt * 128, j0 = jt * 64;

  f32x4 acc[4][6];
#pragma unroll
  for (int a = 0; a < 4; ++a)
#pragma unroll
    for (int b = 0; b < 6; ++b) acc[a][b] = (f32x4){0.f, 0.f, 0.f, 0.f};

  for (int kt = 0; kt < KTILES; ++kt) {
    int k0 = kt * 32;
#pragma unroll
    for (int i = 0; i < 4; ++i) {
      int q = i * 256 + tid;
      int m = q >> 3, kk = (q & 7) * 4;
      int k = k0 + kk;
      const float* src = (k < INSZ) ? (x + (size_t)(m0 + m) * INSZ + k)
                                    : (h + (size_t)(m0 + m) * HID + (k - INSZ));
      float4 v = *(const float4*)src;
      u16x4 o;
      o.x = f32_to_bf16(v.x); o.y = f32_to_bf16(v.y);
      o.z = f32_to_bf16(v.z); o.w = f32_to_bf16(v.w);
      *(u16x4*)(As + m * 36 + kk) = o;
    }
#pragma unroll
    for (int i = 0; i < 6; ++i) {
      int q = i * 256 + tid;
      int n = q % 192, kq = (q / 192) * 4;
      int col = (n >> 6) * HID + j0 + (n & 63);
      float vv[4];
#pragma unroll
      for (int t = 0; t < 4; ++t) {
        int k = k0 + kq + t;
        vv[t] = (k < INSZ) ? W[(size_t)k * NG + col]
                           : Wh[(size_t)(k - INSZ) * NG + col];
      }
      u16x4 o;
      o.x = f32_to_bf16(vv[0]); o.y = f32_to_bf16(vv[1]);
      o.z = f32_to_bf16(vv[2]); o.w = f32_to_bf16(vv[3]);
      *(u16x4*)(Bs + n * 36 + kq) = o;
    }
    __syncthreads();
    short8 af[4], bf[6];
#pragma unroll
    for (int mi = 0; mi < 4; ++mi) {
      int base = (wm * 64 + mi * 16 + l16) * 36 + quad * 8;
      short4v lo = *(const short4v*)(As + base);
      short4v hi = *(const short4v*)(As + base + 4);
      af[mi] = __builtin_shufflevector(lo, hi, 0, 1, 2, 3, 4, 5, 6, 7);
    }
#pragma unroll
    for (int g = 0; g < 3; ++g)
#pragma unroll
      for (int p = 0; p < 2; ++p) {
        int base = (g * 64 + (2 * wn + p) * 16 + l16) * 36 + quad * 8;
        short4v lo = *(const short4v*)(Bs + base);
        short4v hi = *(const short4v*)(Bs + base + 4);
        bf[g * 2 + p] = __builtin_shufflevector(lo, hi, 0, 1, 2, 3, 4, 5, 6, 7);
      }
#pragma unroll
    for (int mi = 0; mi < 4; ++mi)
#pragma unroll
      for (int f = 0; f < 6; ++f)
        acc[mi][f] =
            __builtin_amdgcn_mfma_f32_16x16x32_bf16(af[mi], bf[f], acc[mi][f], 0, 0, 0);
    __syncthreads();
  }
  lstm_epilogue(acc, m0, j0, wm, wn, quad, l16, bias, c0, out);
}

extern "C" void kernel_launch(void* const* d_in, const int* in_sizes, int n_in,
                              void* d_out, int out_size, void* d_ws, size_t ws_size,
                              hipStream_t stream) {
  const float* x    = (const float*)d_in[0];
  const float* h0   = (const float*)d_in[1];
  const float* c0   = (const float*)d_in[2];
  const float* W    = (const float*)d_in[3];
  const float* Wh   = (const float*)d_in[4];
  const float* bias = (const float*)d_in[5];
  float* out = (float*)d_out;

  const size_t needA = (size_t)KTOT * BATCH * 2;  // 48 MB
  const size_t needB = (size_t)KTOT * NG * 2;     // 36 MB
  if (ws_size >= needA + needB) {
    unsigned short* Ap = (unsigned short*)d_ws;
    unsigned short* Bp = Ap + (size_t)KTOT * BATCH;
    pack_a_kernel<<<24576, 256, 0, stream>>>(x, h0, Ap);
    pack_b_kernel<<<1152, 256, 0, stream>>>(W, Wh, Bp);
    gemm_stream_kernel<<<2048, 256, 0, stream>>>(Ap, Bp, bias, c0, out);
  } else {
    gemm_f32_kernel<<<2048, 256, 0, stream>>>(x, h0, W, Wh, bias, c0, out);
  }
}